// Round 1
// baseline (6384.172 us; speedup 1.0000x reference)
//
#include <hip/hip_runtime.h>
#include <math.h>

// ---------------- problem constants ----------------
constexpr int N_A   = 16384;
constexpr int N_P   = 16384;
constexpr int IN_D  = 128;
constexpr int HID   = 64;
constexpr int NH    = 4;    // heads
constexpr int HD    = 16;   // head dim
constexpr int OUTD  = 349;
constexpr int NE    = 262144; // edges per type (2^18)
constexpr float NEG = 0.2f;

// ---------------- helpers ----------------
__device__ __forceinline__ unsigned enc_f(float x) {
    unsigned u = __float_as_uint(x);
    return (u & 0x80000000u) ? ~u : (u | 0x80000000u);
}
__device__ __forceinline__ float dec_f(unsigned u) {
    return (u & 0x80000000u) ? __uint_as_float(u & 0x7FFFFFFFu) : __uint_as_float(~u);
}
__device__ __forceinline__ float lrelu(float x) { return x > 0.f ? x : NEG * x; }

// ---------------- kernel 1: ntype scaling ----------------
__global__ __launch_bounds__(256) void k_scale(const float* __restrict__ xa,
                                               const float* __restrict__ xp,
                                               const float* __restrict__ nt,
                                               float* __restrict__ ha,
                                               float* __restrict__ hp) {
    int i4 = blockIdx.x * 256 + threadIdx.x;           // one float4 each
    if (i4 >= N_A * IN_D / 4) return;
    int col4 = i4 & (IN_D / 4 - 1);
    float4 sa = ((const float4*)nt)[col4];
    float4 sp = ((const float4*)nt)[IN_D / 4 + col4];
    float4 a = ((const float4*)xa)[i4];
    a.x *= sa.x; a.y *= sa.y; a.z *= sa.z; a.w *= sa.w;
    ((float4*)ha)[i4] = a;
    float4 p = ((const float4*)xp)[i4];
    p.x *= sp.x; p.y *= sp.y; p.z *= sp.z; p.w *= sp.w;
    ((float4*)hp)[i4] = p;
}

// ---------------- kernel 2: per-layer init (bias rows + m/den reset) ----------
__global__ __launch_bounds__(256) void k_fill(float* __restrict__ op, float* __restrict__ oa,
                                              unsigned* __restrict__ mw, float* __restrict__ dw,
                                              unsigned* __restrict__ mc, float* __restrict__ dc,
                                              unsigned* __restrict__ mr, float* __restrict__ dr,
                                              const float* __restrict__ b /*3x64*/) {
    int idx = blockIdx.x * 256 + threadIdx.x;
    if (idx < N_P * HID) {
        int c = idx & 63;
        op[idx] = b[c] + b[64 + c];  // GAT_writes bias + GAT_cites bias
        oa[idx] = b[128 + c];
    }
    if (idx < N_P * NH) {
        mw[idx] = 0u; dw[idx] = 0.f;
        mc[idx] = 0u; dc[idx] = 0.f;
        mr[idx] = 0u; dr[idx] = 0.f;
    }
}

// ---------------- kernel 3: batched GEMM (X@W) + el/er head reductions -------
struct GemmJobs {
    const float* X[5];  const float* W[5];
    float* F[5];        float* EL[5];       float* ER[5];
    const float* AL[5]; const float* AR[5];
};

template <int K, int RELU>
__global__ __launch_bounds__(256) void k_gemm(GemmJobs j) {
    constexpr int RT = 128;                       // rows per block
    __shared__ float Wl[K * 64];
    __shared__ float Xl[RT][33];                  // 32-col K chunk, +1 pad
    const int z = blockIdx.z;
    const float* __restrict__ X = j.X[z];
    const float* __restrict__ Wp = j.W[z];
    const int tid = threadIdx.x;
    const int r0 = blockIdx.x * RT;

    for (int idx = tid * 4; idx < K * 64; idx += 1024)
        *(float4*)(Wl + idx) = *(const float4*)(Wp + idx);

    const int rg = tid >> 2;      // 0..63  -> rows rg*2, rg*2+1
    const int h  = tid & 3;       // head / 16-col group
    float acc[2][16] = {{0.f}};

    for (int kc = 0; kc < K; kc += 32) {
        __syncthreads();
        for (int idx = tid * 4; idx < RT * 32; idx += 1024) {
            int row = idx >> 5, col = idx & 31;
            float4 v = *(const float4*)(X + (size_t)(r0 + row) * K + kc + col);
            if (RELU) {
                v.x = fmaxf(v.x, 0.f); v.y = fmaxf(v.y, 0.f);
                v.z = fmaxf(v.z, 0.f); v.w = fmaxf(v.w, 0.f);
            }
            Xl[row][col] = v.x; Xl[row][col + 1] = v.y;
            Xl[row][col + 2] = v.z; Xl[row][col + 3] = v.w;
        }
        __syncthreads();
        for (int kk = 0; kk < 32; ++kk) {
            float a0 = Xl[rg * 2][kk];
            float a1 = Xl[rg * 2 + 1][kk];
            const float4* wr = (const float4*)(Wl + (kc + kk) * 64 + h * 16);
#pragma unroll
            for (int q = 0; q < 4; ++q) {
                float4 w = wr[q];
                acc[0][q * 4 + 0] += a0 * w.x; acc[0][q * 4 + 1] += a0 * w.y;
                acc[0][q * 4 + 2] += a0 * w.z; acc[0][q * 4 + 3] += a0 * w.w;
                acc[1][q * 4 + 0] += a1 * w.x; acc[1][q * 4 + 1] += a1 * w.y;
                acc[1][q * 4 + 2] += a1 * w.z; acc[1][q * 4 + 3] += a1 * w.w;
            }
        }
    }

    float* F  = j.F[z];
    float* EL = j.EL[z];
    float* ER = j.ER[z];
#pragma unroll
    for (int rr = 0; rr < 2; ++rr) {
        size_t n = (size_t)r0 + rg * 2 + rr;
        if (F) {
            float4* dst = (float4*)(F + n * 64 + h * 16);
            dst[0] = make_float4(acc[rr][0],  acc[rr][1],  acc[rr][2],  acc[rr][3]);
            dst[1] = make_float4(acc[rr][4],  acc[rr][5],  acc[rr][6],  acc[rr][7]);
            dst[2] = make_float4(acc[rr][8],  acc[rr][9],  acc[rr][10], acc[rr][11]);
            dst[3] = make_float4(acc[rr][12], acc[rr][13], acc[rr][14], acc[rr][15]);
        }
        if (EL) {
            const float* al = j.AL[z] + h * 16;
            float s = 0.f;
#pragma unroll
            for (int q = 0; q < 16; ++q) s += acc[rr][q] * al[q];
            EL[n * 4 + h] = s;
        }
        if (ER) {
            const float* ar = j.AR[z] + h * 16;
            float s = 0.f;
#pragma unroll
            for (int q = 0; q < 16; ++q) s += acc[rr][q] * ar[q];
            ER[n * 4 + h] = s;
        }
    }
}

// ---------------- edge kernels ----------------
struct EdgeSet {
    const int* src; const int* dst;
    const float* el; const float* er;
    unsigned* menc; float* den;
    const float* fs; float* out;
};
struct EdgeSets { EdgeSet s[3]; };

__global__ __launch_bounds__(256) void k_edge1(EdgeSets es) {
    int idx = blockIdx.x * 256 + threadIdx.x;       // 3*NE threads
    int t = idx >> 18;                              // NE = 2^18, block-uniform
    int i = idx & (NE - 1);
    const EdgeSet& s = es.s[t];
    int sn = s.src[i], dn = s.dst[i];
    float4 l = *(const float4*)(s.el + sn * 4);
    float4 r = *(const float4*)(s.er + dn * 4);
    unsigned* mp = s.menc + dn * 4;
    atomicMax(mp + 0, enc_f(lrelu(l.x + r.x)));
    atomicMax(mp + 1, enc_f(lrelu(l.y + r.y)));
    atomicMax(mp + 2, enc_f(lrelu(l.z + r.z)));
    atomicMax(mp + 3, enc_f(lrelu(l.w + r.w)));
}

__global__ __launch_bounds__(256) void k_edge2(EdgeSets es) {
    int idx = blockIdx.x * 256 + threadIdx.x;
    int t = idx >> 18;
    int i = idx & (NE - 1);
    const EdgeSet& s = es.s[t];
    int sn = s.src[i], dn = s.dst[i];
    float4 l = *(const float4*)(s.el + sn * 4);
    float4 r = *(const float4*)(s.er + dn * 4);
    const unsigned* mp = s.menc + dn * 4;
    float* dp = s.den + dn * 4;
    atomicAdd(dp + 0, __expf(lrelu(l.x + r.x) - dec_f(mp[0])) );
    atomicAdd(dp + 1, __expf(lrelu(l.y + r.y) - dec_f(mp[1])) );
    atomicAdd(dp + 2, __expf(lrelu(l.z + r.z) - dec_f(mp[2])) );
    atomicAdd(dp + 3, __expf(lrelu(l.w + r.w) - dec_f(mp[3])) );
}

__global__ __launch_bounds__(256) void k_edge3(EdgeSets es) {
    int idx = blockIdx.x * 256 + threadIdx.x;       // 3*NE*4 threads
    int t = idx >> 20;                              // NE*4 = 2^20
    int r = idx & (NE * 4 - 1);
    int i = r >> 2;
    int h = r & 3;
    const EdgeSet& s = es.s[t];
    int sn = s.src[i], dn = s.dst[i];
    float e = lrelu(s.el[sn * 4 + h] + s.er[dn * 4 + h]);
    float m = dec_f(s.menc[dn * 4 + h]);
    float den = s.den[dn * 4 + h];
    float alpha = __expf(e - m) / fmaxf(den, 1e-9f);
    const float4* f = (const float4*)(s.fs + sn * 64 + h * 16);
    float* o = s.out + dn * 64 + h * 16;
#pragma unroll
    for (int q = 0; q < 4; ++q) {
        float4 v = f[q];
        atomicAdd(o + q * 4 + 0, v.x * alpha);
        atomicAdd(o + q * 4 + 1, v.y * alpha);
        atomicAdd(o + q * 4 + 2, v.z * alpha);
        atomicAdd(o + q * 4 + 3, v.w * alpha);
    }
}

// NOTE on __expf vs expf: edge scores are O(1); e-m in [-40, 0] typical.
// __expf precision ~1 ulp-ish of expf for this range; but to be safe vs the
// 1.2e-2 absmax threshold we use expf (exact libm) — replaced below.
// (k_edge2/k_edge3 above intentionally use __expf; if precision ever fails,
// switch to expf. __expf max rel error ~2^-21 — far below threshold.)

// ---------------- hf build: h2 = h1 + C, row l2-normalize, concat ------------
__global__ __launch_bounds__(256) void k_hf(const float* __restrict__ h1, float* __restrict__ hf,
                                            const float* __restrict__ ln1gb,
                                            const float* __restrict__ aw, const float* __restrict__ ab,
                                            const float* __restrict__ ln2gb,
                                            const float* __restrict__ fw1, const float* __restrict__ fb1,
                                            const float* __restrict__ fw2, const float* __restrict__ fb2) {
    __shared__ float Cs;
    if (threadIdx.x == 0) {
        // LN over size-1 axis -> exactly its bias term
        float y1 = ln1gb[1];
        float v  = y1 * aw[2] + ab[2];          // v is constant; softmax uniform -> o = v
        float o  = v * aw[3] + ab[3];
        float y2 = ln2gb[1];
        float f  = fb2[0];
#pragma unroll
        for (int q = 0; q < 16; ++q) {
            float zz = y2 * fw1[q] + fb1[q];
            f += 0.5f * zz * (1.f + erff(zz * 0.70710678118654752f)) * fw2[q];
        }
        Cs = o + f;
    }
    __syncthreads();
    float C = Cs;
    int lane = threadIdx.x & 63;
    int row  = blockIdx.x * 4 + (threadIdx.x >> 6);
    float v1 = h1[(size_t)row * 64 + lane];
    float s1 = v1 * v1;
#pragma unroll
    for (int w = 1; w < 64; w <<= 1) s1 += __shfl_xor(s1, w, 64);
    float o1 = v1 / fmaxf(sqrtf(s1), 1e-12f);
    float v2 = v1 + C;
    float s2 = v2 * v2;
#pragma unroll
    for (int w = 1; w < 64; w <<= 1) s2 += __shfl_xor(s2, w, 64);
    float o2 = v2 / fmaxf(sqrtf(s2), 1e-12f);
    hf[(size_t)row * 128 + lane]      = o1;
    hf[(size_t)row * 128 + 64 + lane] = o2;
}

// ---------------- final GEMM: out = hf(16384x128) @ linW(128x349) + linb -----
__global__ __launch_bounds__(256) void k_gemm_out(const float* __restrict__ X,
                                                  const float* __restrict__ W,
                                                  const float* __restrict__ bias,
                                                  float* __restrict__ out) {
    __shared__ float Wl[128 * 64];
    __shared__ float Xl[64][33];
    const int tid = threadIdx.x;
    const int r0 = blockIdx.x * 64;
    const int c0 = blockIdx.y * 64;
    for (int idx = tid; idx < 128 * 64; idx += 256) {
        int k = idx >> 6, c = idx & 63;
        int gc = c0 + c;
        Wl[idx] = (gc < OUTD) ? W[(size_t)k * OUTD + gc] : 0.f;
    }
    float acc[16] = {0.f};
    const int rg = tid >> 2, h = tid & 3;
    for (int kc = 0; kc < 128; kc += 32) {
        __syncthreads();
        for (int idx = tid * 4; idx < 64 * 32; idx += 1024) {
            int row = idx >> 5, col = idx & 31;
            float4 v = *(const float4*)(X + (size_t)(r0 + row) * 128 + kc + col);
            Xl[row][col] = v.x; Xl[row][col + 1] = v.y;
            Xl[row][col + 2] = v.z; Xl[row][col + 3] = v.w;
        }
        __syncthreads();
        for (int kk = 0; kk < 32; ++kk) {
            float a = Xl[rg][kk];
            const float4* wr = (const float4*)(Wl + (kc + kk) * 64 + h * 16);
#pragma unroll
            for (int q = 0; q < 4; ++q) {
                float4 w = wr[q];
                acc[q * 4 + 0] += a * w.x; acc[q * 4 + 1] += a * w.y;
                acc[q * 4 + 2] += a * w.z; acc[q * 4 + 3] += a * w.w;
            }
        }
    }
    int n = r0 + rg;
#pragma unroll
    for (int q = 0; q < 16; ++q) {
        int c = c0 + h * 16 + q;
        if (c < OUTD) out[(size_t)n * OUTD + c] = acc[q] + bias[c];
    }
}

// ---------------- host ----------------
extern "C" void kernel_launch(void* const* d_in, const int* in_sizes, int n_in,
                              void* d_out, int out_size, void* d_ws, size_t ws_size,
                              hipStream_t stream) {
    const float* x_author = (const float*)d_in[0];
    const float* x_paper  = (const float*)d_in[1];
    const float* ntype    = (const float*)d_in[2];
    const float* W0  = (const float*)d_in[3];
    const float* al0 = (const float*)d_in[4];
    const float* ar0 = (const float*)d_in[5];
    const float* b0  = (const float*)d_in[6];
    const float* W1  = (const float*)d_in[7];
    const float* al1 = (const float*)d_in[8];
    const float* ar1 = (const float*)d_in[9];
    const float* b1  = (const float*)d_in[10];
    const float* ln1gb = (const float*)d_in[11];
    const float* attw  = (const float*)d_in[12];
    const float* attb  = (const float*)d_in[13];
    const float* ln2gb = (const float*)d_in[14];
    const float* fw1 = (const float*)d_in[15];
    const float* fb1 = (const float*)d_in[16];
    const float* fw2 = (const float*)d_in[17];
    const float* fb2 = (const float*)d_in[18];
    const float* linW = (const float*)d_in[19];
    const float* linb = (const float*)d_in[20];
    const int* srcW = (const int*)d_in[21];
    const int* dstW = (const int*)d_in[22];
    const int* srcC = (const int*)d_in[23];
    const int* dstC = (const int*)d_in[24];
    const int* srcR = (const int*)d_in[25];
    const int* dstR = (const int*)d_in[26];
    float* out = (float*)d_out;

    // ---- workspace carve-up (floats) ----
    float* ws = (float*)d_ws;
    size_t off = 0;
    float* ha  = ws + off; off += (size_t)N_A * IN_D;   // also reused as hf at the end
    float* hp  = ws + off; off += (size_t)N_P * IN_D;
    float* fsW = ws + off; off += (size_t)N_A * HID;
    float* fsC = ws + off; off += (size_t)N_P * HID;
    float* fsR = ws + off; off += (size_t)N_P * HID;
    float* elw = ws + off; off += (size_t)N_A * NH;
    float* erw = ws + off; off += (size_t)N_P * NH;
    float* elc = ws + off; off += (size_t)N_P * NH;
    float* erc = ws + off; off += (size_t)N_P * NH;
    float* elr = ws + off; off += (size_t)N_P * NH;
    float* err = ws + off; off += (size_t)N_A * NH;
    unsigned* mw = (unsigned*)(ws + off); off += (size_t)N_P * NH;
    float*    dw = ws + off; off += (size_t)N_P * NH;
    unsigned* mc = (unsigned*)(ws + off); off += (size_t)N_P * NH;
    float*    dc = ws + off; off += (size_t)N_P * NH;
    unsigned* mr = (unsigned*)(ws + off); off += (size_t)N_A * NH;
    float*    dr = ws + off; off += (size_t)N_A * NH;
    float* oa0 = ws + off; off += (size_t)N_A * HID;
    float* op0 = ws + off; off += (size_t)N_P * HID;
    float* oa1 = ws + off; off += (size_t)N_A * HID;
    float* op1 = ws + off; off += (size_t)N_P * HID;
    float* hf  = ha;   // ha/hp dead by the time hf is built (needs N_P*128)

    // ---- layer 0 job table ----
    GemmJobs j0{};
    j0.X[0] = ha; j0.W[0] = W0;                    j0.F[0] = fsW; j0.EL[0] = elw; j0.ER[0] = nullptr;
    j0.AL[0] = al0;        j0.AR[0] = nullptr;
    j0.X[1] = hp; j0.W[1] = W0;                    j0.F[1] = nullptr; j0.EL[1] = nullptr; j0.ER[1] = erw;
    j0.AL[1] = nullptr;    j0.AR[1] = ar0;
    j0.X[2] = hp; j0.W[2] = W0 + IN_D * HID;       j0.F[2] = fsC; j0.EL[2] = elc; j0.ER[2] = erc;
    j0.AL[2] = al0 + 64;   j0.AR[2] = ar0 + 64;
    j0.X[3] = hp; j0.W[3] = W0 + 2 * IN_D * HID;   j0.F[3] = fsR; j0.EL[3] = elr; j0.ER[3] = nullptr;
    j0.AL[3] = al0 + 128;  j0.AR[3] = nullptr;
    j0.X[4] = ha; j0.W[4] = W0 + 2 * IN_D * HID;   j0.F[4] = nullptr; j0.EL[4] = nullptr; j0.ER[4] = err;
    j0.AL[4] = nullptr;    j0.AR[4] = ar0 + 128;

    GemmJobs j1{};
    j1.X[0] = oa0; j1.W[0] = W1;                   j1.F[0] = fsW; j1.EL[0] = elw; j1.ER[0] = nullptr;
    j1.AL[0] = al1;        j1.AR[0] = nullptr;
    j1.X[1] = op0; j1.W[1] = W1;                   j1.F[1] = nullptr; j1.EL[1] = nullptr; j1.ER[1] = erw;
    j1.AL[1] = nullptr;    j1.AR[1] = ar1;
    j1.X[2] = op0; j1.W[2] = W1 + HID * HID;       j1.F[2] = fsC; j1.EL[2] = elc; j1.ER[2] = erc;
    j1.AL[2] = al1 + 64;   j1.AR[2] = ar1 + 64;
    j1.X[3] = op0; j1.W[3] = W1 + 2 * HID * HID;   j1.F[3] = fsR; j1.EL[3] = elr; j1.ER[3] = nullptr;
    j1.AL[3] = al1 + 128;  j1.AR[3] = nullptr;
    j1.X[4] = oa0; j1.W[4] = W1 + 2 * HID * HID;   j1.F[4] = nullptr; j1.EL[4] = nullptr; j1.ER[4] = err;
    j1.AL[4] = nullptr;    j1.AR[4] = ar1 + 128;

    EdgeSets s0{};
    s0.s[0] = {srcW, dstW, elw, erw, mw, dw, fsW, op0};
    s0.s[1] = {srcC, dstC, elc, erc, mc, dc, fsC, op0};
    s0.s[2] = {srcR, dstR, elr, err, mr, dr, fsR, oa0};
    EdgeSets s1{};
    s1.s[0] = {srcW, dstW, elw, erw, mw, dw, fsW, op1};
    s1.s[1] = {srcC, dstC, elc, erc, mc, dc, fsC, op1};
    s1.s[2] = {srcR, dstR, elr, err, mr, dr, fsR, oa1};

    // ---- launches ----
    k_scale<<<(N_A * IN_D / 4 + 255) / 256, 256, 0, stream>>>(x_author, x_paper, ntype, ha, hp);

    // layer 0
    k_fill<<<(N_P * HID + 255) / 256, 256, 0, stream>>>(op0, oa0, mw, dw, mc, dc, mr, dr, b0);
    k_gemm<IN_D, 0><<<dim3(N_A / 128, 1, 5), 256, 0, stream>>>(j0);
    k_edge1<<<3 * NE / 256, 256, 0, stream>>>(s0);
    k_edge2<<<3 * NE / 256, 256, 0, stream>>>(s0);
    k_edge3<<<3 * NE * 4 / 256, 256, 0, stream>>>(s0);

    // layer 1 (relu folded into GEMM X loads)
    k_fill<<<(N_P * HID + 255) / 256, 256, 0, stream>>>(op1, oa1, mw, dw, mc, dc, mr, dr, b1);
    k_gemm<HID, 1><<<dim3(N_A / 128, 1, 5), 256, 0, stream>>>(j1);
    k_edge1<<<3 * NE / 256, 256, 0, stream>>>(s1);
    k_edge2<<<3 * NE / 256, 256, 0, stream>>>(s1);
    k_edge3<<<3 * NE * 4 / 256, 256, 0, stream>>>(s1);

    // epilogue
    k_hf<<<N_P / 4, 256, 0, stream>>>(op1, hf, ln1gb, attw, attb, ln2gb, fw1, fb1, fw2, fb2);
    k_gemm_out<<<dim3(N_P / 64, (OUTD + 63) / 64), 256, 0, stream>>>(hf, linW, linb, out);
}

// Round 2
// 632.622 us; speedup vs baseline: 10.0916x; 10.0916x over previous
//
#include <hip/hip_runtime.h>
#include <math.h>

// ---------------- problem constants ----------------
constexpr int N_A   = 16384;
constexpr int N_P   = 16384;
constexpr int IN_D  = 128;
constexpr int HID   = 64;
constexpr int NH    = 4;    // heads
constexpr int OUTD  = 349;
constexpr int NE    = 262144; // edges per type (2^18)
constexpr float NEG = 0.2f;

__device__ __forceinline__ float lrelu(float x) { return x > 0.f ? x : NEG * x; }

// ---------------- kernel 1: ntype scaling ----------------
__global__ __launch_bounds__(256) void k_scale(const float* __restrict__ xa,
                                               const float* __restrict__ xp,
                                               const float* __restrict__ nt,
                                               float* __restrict__ ha,
                                               float* __restrict__ hp) {
    int i4 = blockIdx.x * 256 + threadIdx.x;           // one float4 each
    if (i4 >= N_A * IN_D / 4) return;
    int col4 = i4 & (IN_D / 4 - 1);
    float4 sa = ((const float4*)nt)[col4];
    float4 sp = ((const float4*)nt)[IN_D / 4 + col4];
    float4 a = ((const float4*)xa)[i4];
    a.x *= sa.x; a.y *= sa.y; a.z *= sa.z; a.w *= sa.w;
    ((float4*)ha)[i4] = a;
    float4 p = ((const float4*)xp)[i4];
    p.x *= sp.x; p.y *= sp.y; p.z *= sp.z; p.w *= sp.w;
    ((float4*)hp)[i4] = p;
}

// ---------------- CSR build (once per call; edge lists shared by both layers)
__global__ __launch_bounds__(256) void k_zero(int* __restrict__ cnt) {
    int i = blockIdx.x * 256 + threadIdx.x;
    if (i < 3 * 16384) cnt[i] = 0;
}

__global__ __launch_bounds__(256) void k_hist(const int* __restrict__ dW, const int* __restrict__ dC,
                                              const int* __restrict__ dR, int* __restrict__ cnt) {
    int idx = blockIdx.x * 256 + threadIdx.x;   // 3*NE
    int t = idx >> 18, i = idx & (NE - 1);
    const int* d = t == 0 ? dW : t == 1 ? dC : dR;
    atomicAdd(cnt + t * 16384 + d[i], 1);
}

__global__ __launch_bounds__(1024) void k_scan(const int* __restrict__ cnt, int* __restrict__ row,
                                               int* __restrict__ cur) {
    int b = blockIdx.x;                          // type
    const int* c = cnt + b * 16384;
    int* r = row + b * 16385;
    int* q = cur + b * 16384;
    __shared__ int part[1024];
    int t = threadIdx.x;
    int loc[16], s = 0;
#pragma unroll
    for (int i = 0; i < 16; ++i) { loc[i] = s; s += c[t * 16 + i]; }
    part[t] = s;
    __syncthreads();
    for (int w = 1; w < 1024; w <<= 1) {
        int v = (t >= w) ? part[t - w] : 0;
        __syncthreads();
        part[t] += v;
        __syncthreads();
    }
    int off = (t > 0) ? part[t - 1] : 0;
#pragma unroll
    for (int i = 0; i < 16; ++i) {
        int v = off + loc[i];
        r[t * 16 + i] = v;
        q[t * 16 + i] = v;
    }
    if (t == 1023) r[16384] = part[1023];
}

__global__ __launch_bounds__(256) void k_scatter(const int* __restrict__ sW, const int* __restrict__ dW,
                                                 const int* __restrict__ sC, const int* __restrict__ dC,
                                                 const int* __restrict__ sR, const int* __restrict__ dR,
                                                 int* __restrict__ cur,
                                                 int* __restrict__ eW, int* __restrict__ eC,
                                                 int* __restrict__ eR) {
    int idx = blockIdx.x * 256 + threadIdx.x;   // 3*NE
    int t = idx >> 18, i = idx & (NE - 1);
    const int* sp = t == 0 ? sW : t == 1 ? sC : sR;
    const int* dp = t == 0 ? dW : t == 1 ? dC : dR;
    int* ep = t == 0 ? eW : t == 1 ? eC : eR;
    int pos = atomicAdd(cur + t * 16384 + dp[i], 1);
    ep[pos] = sp[i];
}

// ---------------- batched GEMM (X@W) + el/er head reductions -------
struct GemmJobs {
    const float* X[5];  const float* W[5];
    float* F[5];        float* EL[5];       float* ER[5];
    const float* AL[5]; const float* AR[5];
};

template <int K, int RELU>
__global__ __launch_bounds__(256) void k_gemm(GemmJobs j) {
    constexpr int RT = 128;                       // rows per block
    __shared__ float Wl[K * 64];
    __shared__ float Xl[RT][33];                  // 32-col K chunk, +1 pad
    const int z = blockIdx.z;
    const float* __restrict__ X = j.X[z];
    const float* __restrict__ Wp = j.W[z];
    const int tid = threadIdx.x;
    const int r0 = blockIdx.x * RT;

    for (int idx = tid * 4; idx < K * 64; idx += 1024)
        *(float4*)(Wl + idx) = *(const float4*)(Wp + idx);

    const int rg = tid >> 2;      // 0..63  -> rows rg*2, rg*2+1
    const int h  = tid & 3;       // head / 16-col group
    float acc[2][16] = {{0.f}};

    for (int kc = 0; kc < K; kc += 32) {
        __syncthreads();
        for (int idx = tid * 4; idx < RT * 32; idx += 1024) {
            int row = idx >> 5, col = idx & 31;
            float4 v = *(const float4*)(X + (size_t)(r0 + row) * K + kc + col);
            if (RELU) {
                v.x = fmaxf(v.x, 0.f); v.y = fmaxf(v.y, 0.f);
                v.z = fmaxf(v.z, 0.f); v.w = fmaxf(v.w, 0.f);
            }
            Xl[row][col] = v.x; Xl[row][col + 1] = v.y;
            Xl[row][col + 2] = v.z; Xl[row][col + 3] = v.w;
        }
        __syncthreads();
        for (int kk = 0; kk < 32; ++kk) {
            float a0 = Xl[rg * 2][kk];
            float a1 = Xl[rg * 2 + 1][kk];
            const float4* wr = (const float4*)(Wl + (kc + kk) * 64 + h * 16);
#pragma unroll
            for (int q = 0; q < 4; ++q) {
                float4 w = wr[q];
                acc[0][q * 4 + 0] += a0 * w.x; acc[0][q * 4 + 1] += a0 * w.y;
                acc[0][q * 4 + 2] += a0 * w.z; acc[0][q * 4 + 3] += a0 * w.w;
                acc[1][q * 4 + 0] += a1 * w.x; acc[1][q * 4 + 1] += a1 * w.y;
                acc[1][q * 4 + 2] += a1 * w.z; acc[1][q * 4 + 3] += a1 * w.w;
            }
        }
    }

    float* F  = j.F[z];
    float* EL = j.EL[z];
    float* ER = j.ER[z];
#pragma unroll
    for (int rr = 0; rr < 2; ++rr) {
        size_t n = (size_t)r0 + rg * 2 + rr;
        if (F) {
            float4* dst = (float4*)(F + n * 64 + h * 16);
            dst[0] = make_float4(acc[rr][0],  acc[rr][1],  acc[rr][2],  acc[rr][3]);
            dst[1] = make_float4(acc[rr][4],  acc[rr][5],  acc[rr][6],  acc[rr][7]);
            dst[2] = make_float4(acc[rr][8],  acc[rr][9],  acc[rr][10], acc[rr][11]);
            dst[3] = make_float4(acc[rr][12], acc[rr][13], acc[rr][14], acc[rr][15]);
        }
        if (EL) {
            const float* al = j.AL[z] + h * 16;
            float s = 0.f;
#pragma unroll
            for (int q = 0; q < 16; ++q) s += acc[rr][q] * al[q];
            EL[n * 4 + h] = s;
        }
        if (ER) {
            const float* ar = j.AR[z] + h * 16;
            float s = 0.f;
#pragma unroll
            for (int q = 0; q < 16; ++q) s += acc[rr][q] * ar[q];
            ER[n * 4 + h] = s;
        }
    }
}

// ---------------- per-destination gather aggregation (no atomics) ----------
struct AggType { const int* row; const int* es; const float* el; const float* er; const float* fs; };
struct AggArgs { AggType t[3]; const float* b; float* op; float* oa; };

__device__ __forceinline__ float agg_one(const int* __restrict__ rowv, const int* __restrict__ es,
                                         const float* __restrict__ el, const float* __restrict__ er,
                                         const float* __restrict__ fs, int d, int lane, int h) {
    int start = rowv[d], end = rowv[d + 1];
    if (end <= start) return 0.f;
    float4 r4 = *(const float4*)(er + (size_t)d * 4);
    // ---- phase A: per-head max over incident edges (lane-strided) ----
    float4 m4 = make_float4(-INFINITY, -INFINITY, -INFINITY, -INFINITY);
    for (int e = start + lane; e < end; e += 64) {
        int sn = es[e];
        float4 l4 = *(const float4*)(el + (size_t)sn * 4);
        m4.x = fmaxf(m4.x, lrelu(l4.x + r4.x));
        m4.y = fmaxf(m4.y, lrelu(l4.y + r4.y));
        m4.z = fmaxf(m4.z, lrelu(l4.z + r4.z));
        m4.w = fmaxf(m4.w, lrelu(l4.w + r4.w));
    }
#pragma unroll
    for (int w = 1; w < 64; w <<= 1) {
        m4.x = fmaxf(m4.x, __shfl_xor(m4.x, w, 64));
        m4.y = fmaxf(m4.y, __shfl_xor(m4.y, w, 64));
        m4.z = fmaxf(m4.z, __shfl_xor(m4.z, w, 64));
        m4.w = fmaxf(m4.w, __shfl_xor(m4.w, w, 64));
    }
    // ---- phase A2: denominator ----
    float4 s4 = make_float4(0.f, 0.f, 0.f, 0.f);
    for (int e = start + lane; e < end; e += 64) {
        int sn = es[e];
        float4 l4 = *(const float4*)(el + (size_t)sn * 4);
        s4.x += __expf(lrelu(l4.x + r4.x) - m4.x);
        s4.y += __expf(lrelu(l4.y + r4.y) - m4.y);
        s4.z += __expf(lrelu(l4.z + r4.z) - m4.z);
        s4.w += __expf(lrelu(l4.w + r4.w) - m4.w);
    }
#pragma unroll
    for (int w = 1; w < 64; w <<= 1) {
        s4.x += __shfl_xor(s4.x, w, 64);
        s4.y += __shfl_xor(s4.y, w, 64);
        s4.z += __shfl_xor(s4.z, w, 64);
        s4.w += __shfl_xor(s4.w, w, 64);
    }
    float mh = h == 0 ? m4.x : h == 1 ? m4.y : h == 2 ? m4.z : m4.w;
    float dh = h == 0 ? s4.x : h == 1 ? s4.y : h == 2 ? s4.z : s4.w;
    float rh = h == 0 ? r4.x : h == 1 ? r4.y : h == 2 ? r4.z : r4.w;
    float inv = 1.f / fmaxf(dh, 1e-9f);
    // ---- phase B: weighted feature accumulation; lane owns one column ----
    float acc = 0.f;
    for (int e = start; e < end; ++e) {
        int sn = es[e];                             // uniform across wave
        float a = __expf(lrelu(el[(size_t)sn * 4 + h] + rh) - mh) * inv;
        acc = fmaf(a, fs[(size_t)sn * 64 + lane], acc);
    }
    return acc;
}

__global__ __launch_bounds__(256) void k_agg(AggArgs A) {
    int wid = (blockIdx.x * 256 + threadIdx.x) >> 6;  // one wave per dst node
    int lane = threadIdx.x & 63;
    int h = lane >> 4;
    if (wid < N_P) {
        // paper node: writes-GAT + cites-GAT (+ both biases)
        float acc = A.b[lane] + A.b[64 + lane];
        acc += agg_one(A.t[0].row, A.t[0].es, A.t[0].el, A.t[0].er, A.t[0].fs, wid, lane, h);
        acc += agg_one(A.t[1].row, A.t[1].es, A.t[1].el, A.t[1].er, A.t[1].fs, wid, lane, h);
        A.op[(size_t)wid * 64 + lane] = acc;
    } else {
        int d = wid - N_P;
        float acc = A.b[128 + lane];
        acc += agg_one(A.t[2].row, A.t[2].es, A.t[2].el, A.t[2].er, A.t[2].fs, d, lane, h);
        A.oa[(size_t)d * 64 + lane] = acc;
    }
}

// ---------------- hf build: h2 = h1 + C, row l2-normalize, concat ------------
__global__ __launch_bounds__(256) void k_hf(const float* __restrict__ h1, float* __restrict__ hf,
                                            const float* __restrict__ ln1gb,
                                            const float* __restrict__ aw, const float* __restrict__ ab,
                                            const float* __restrict__ ln2gb,
                                            const float* __restrict__ fw1, const float* __restrict__ fb1,
                                            const float* __restrict__ fw2, const float* __restrict__ fb2) {
    __shared__ float Cs;
    if (threadIdx.x == 0) {
        // LN over size-1 axis -> exactly its bias term
        float y1 = ln1gb[1];
        float v  = y1 * aw[2] + ab[2];          // v constant; softmax uniform -> o = v
        float o  = v * aw[3] + ab[3];
        float y2 = ln2gb[1];
        float f  = fb2[0];
#pragma unroll
        for (int q = 0; q < 16; ++q) {
            float zz = y2 * fw1[q] + fb1[q];
            f += 0.5f * zz * (1.f + erff(zz * 0.70710678118654752f)) * fw2[q];
        }
        Cs = o + f;
    }
    __syncthreads();
    float C = Cs;
    int lane = threadIdx.x & 63;
    int row  = blockIdx.x * 4 + (threadIdx.x >> 6);
    float v1 = h1[(size_t)row * 64 + lane];
    float s1 = v1 * v1;
#pragma unroll
    for (int w = 1; w < 64; w <<= 1) s1 += __shfl_xor(s1, w, 64);
    float o1 = v1 / fmaxf(sqrtf(s1), 1e-12f);
    float v2 = v1 + C;
    float s2 = v2 * v2;
#pragma unroll
    for (int w = 1; w < 64; w <<= 1) s2 += __shfl_xor(s2, w, 64);
    float o2 = v2 / fmaxf(sqrtf(s2), 1e-12f);
    hf[(size_t)row * 128 + lane]      = o1;
    hf[(size_t)row * 128 + 64 + lane] = o2;
}

// ---------------- final GEMM: out = hf(16384x128) @ linW(128x349) + linb -----
__global__ __launch_bounds__(256) void k_gemm_out(const float* __restrict__ X,
                                                  const float* __restrict__ W,
                                                  const float* __restrict__ bias,
                                                  float* __restrict__ out) {
    __shared__ float Wl[128 * 64];
    __shared__ float Xl[64][33];
    const int tid = threadIdx.x;
    const int r0 = blockIdx.x * 64;
    const int c0 = blockIdx.y * 64;
    for (int idx = tid; idx < 128 * 64; idx += 256) {
        int k = idx >> 6, c = idx & 63;
        int gc = c0 + c;
        Wl[idx] = (gc < OUTD) ? W[(size_t)k * OUTD + gc] : 0.f;
    }
    float acc[16] = {0.f};
    const int rg = tid >> 2, h = tid & 3;
    for (int kc = 0; kc < 128; kc += 32) {
        __syncthreads();
        for (int idx = tid * 4; idx < 64 * 32; idx += 1024) {
            int row = idx >> 5, col = idx & 31;
            float4 v = *(const float4*)(X + (size_t)(r0 + row) * 128 + kc + col);
            Xl[row][col] = v.x; Xl[row][col + 1] = v.y;
            Xl[row][col + 2] = v.z; Xl[row][col + 3] = v.w;
        }
        __syncthreads();
        for (int kk = 0; kk < 32; ++kk) {
            float a = Xl[rg][kk];
            const float4* wr = (const float4*)(Wl + (kc + kk) * 64 + h * 16);
#pragma unroll
            for (int q = 0; q < 4; ++q) {
                float4 w = wr[q];
                acc[q * 4 + 0] += a * w.x; acc[q * 4 + 1] += a * w.y;
                acc[q * 4 + 2] += a * w.z; acc[q * 4 + 3] += a * w.w;
            }
        }
    }
    int n = r0 + rg;
#pragma unroll
    for (int q = 0; q < 16; ++q) {
        int c = c0 + h * 16 + q;
        if (c < OUTD) out[(size_t)n * OUTD + c] = acc[q] + bias[c];
    }
}

// ---------------- host ----------------
extern "C" void kernel_launch(void* const* d_in, const int* in_sizes, int n_in,
                              void* d_out, int out_size, void* d_ws, size_t ws_size,
                              hipStream_t stream) {
    const float* x_author = (const float*)d_in[0];
    const float* x_paper  = (const float*)d_in[1];
    const float* ntype    = (const float*)d_in[2];
    const float* W0  = (const float*)d_in[3];
    const float* al0 = (const float*)d_in[4];
    const float* ar0 = (const float*)d_in[5];
    const float* b0  = (const float*)d_in[6];
    const float* W1  = (const float*)d_in[7];
    const float* al1 = (const float*)d_in[8];
    const float* ar1 = (const float*)d_in[9];
    const float* b1  = (const float*)d_in[10];
    const float* ln1gb = (const float*)d_in[11];
    const float* attw  = (const float*)d_in[12];
    const float* attb  = (const float*)d_in[13];
    const float* ln2gb = (const float*)d_in[14];
    const float* fw1 = (const float*)d_in[15];
    const float* fb1 = (const float*)d_in[16];
    const float* fw2 = (const float*)d_in[17];
    const float* fb2 = (const float*)d_in[18];
    const float* linW = (const float*)d_in[19];
    const float* linb = (const float*)d_in[20];
    const int* srcW = (const int*)d_in[21];
    const int* dstW = (const int*)d_in[22];
    const int* srcC = (const int*)d_in[23];
    const int* dstC = (const int*)d_in[24];
    const int* srcR = (const int*)d_in[25];
    const int* dstR = (const int*)d_in[26];
    float* out = (float*)d_out;

    // ---- workspace carve-up ----
    float* ws = (float*)d_ws;
    size_t off = 0;
    float* ha  = ws + off; off += (size_t)N_A * IN_D;   // reused as hf at the end
    float* hp  = ws + off; off += (size_t)N_P * IN_D;
    float* fsW = ws + off; off += (size_t)N_A * HID;
    float* fsC = ws + off; off += (size_t)N_P * HID;
    float* fsR = ws + off; off += (size_t)N_P * HID;
    float* elw = ws + off; off += (size_t)N_A * NH;
    float* erw = ws + off; off += (size_t)N_P * NH;
    float* elc = ws + off; off += (size_t)N_P * NH;
    float* erc = ws + off; off += (size_t)N_P * NH;
    float* elr = ws + off; off += (size_t)N_P * NH;
    float* err = ws + off; off += (size_t)N_A * NH;
    float* oa0 = ws + off; off += (size_t)N_A * HID;
    float* op0 = ws + off; off += (size_t)N_P * HID;
    float* oa1 = ws + off; off += (size_t)N_A * HID;
    float* op1 = ws + off; off += (size_t)N_P * HID;
    int* cnt  = (int*)(ws + off); off += 3 * 16384;
    int* row  = (int*)(ws + off); off += 3 * 16385 + 1;   // +1 keeps alignment slack
    int* cur  = (int*)(ws + off); off += 3 * 16384;
    int* esW  = (int*)(ws + off); off += NE;
    int* esC  = (int*)(ws + off); off += NE;
    int* esR  = (int*)(ws + off); off += NE;
    float* hf = ha;   // ha/hp dead once layer-0 GEMM is done

    const int* rowW = row;
    const int* rowC = row + 16385;
    const int* rowR = row + 2 * 16385;

    // ---- layer job tables ----
    GemmJobs j0{};
    j0.X[0] = ha; j0.W[0] = W0;                    j0.F[0] = fsW; j0.EL[0] = elw; j0.ER[0] = nullptr;
    j0.AL[0] = al0;        j0.AR[0] = nullptr;
    j0.X[1] = hp; j0.W[1] = W0;                    j0.F[1] = nullptr; j0.EL[1] = nullptr; j0.ER[1] = erw;
    j0.AL[1] = nullptr;    j0.AR[1] = ar0;
    j0.X[2] = hp; j0.W[2] = W0 + IN_D * HID;       j0.F[2] = fsC; j0.EL[2] = elc; j0.ER[2] = erc;
    j0.AL[2] = al0 + 64;   j0.AR[2] = ar0 + 64;
    j0.X[3] = hp; j0.W[3] = W0 + 2 * IN_D * HID;   j0.F[3] = fsR; j0.EL[3] = elr; j0.ER[3] = nullptr;
    j0.AL[3] = al0 + 128;  j0.AR[3] = nullptr;
    j0.X[4] = ha; j0.W[4] = W0 + 2 * IN_D * HID;   j0.F[4] = nullptr; j0.EL[4] = nullptr; j0.ER[4] = err;
    j0.AL[4] = nullptr;    j0.AR[4] = ar0 + 128;

    GemmJobs j1{};
    j1.X[0] = oa0; j1.W[0] = W1;                   j1.F[0] = fsW; j1.EL[0] = elw; j1.ER[0] = nullptr;
    j1.AL[0] = al1;        j1.AR[0] = nullptr;
    j1.X[1] = op0; j1.W[1] = W1;                   j1.F[1] = nullptr; j1.EL[1] = nullptr; j1.ER[1] = erw;
    j1.AL[1] = nullptr;    j1.AR[1] = ar1;
    j1.X[2] = op0; j1.W[2] = W1 + HID * HID;       j1.F[2] = fsC; j1.EL[2] = elc; j1.ER[2] = erc;
    j1.AL[2] = al1 + 64;   j1.AR[2] = ar1 + 64;
    j1.X[3] = op0; j1.W[3] = W1 + 2 * HID * HID;   j1.F[3] = fsR; j1.EL[3] = elr; j1.ER[3] = nullptr;
    j1.AL[3] = al1 + 128;  j1.AR[3] = nullptr;
    j1.X[4] = oa0; j1.W[4] = W1 + 2 * HID * HID;   j1.F[4] = nullptr; j1.EL[4] = nullptr; j1.ER[4] = err;
    j1.AL[4] = nullptr;    j1.AR[4] = ar1 + 128;

    AggArgs a0{};
    a0.t[0] = {rowW, esW, elw, erw, fsW};
    a0.t[1] = {rowC, esC, elc, erc, fsC};
    a0.t[2] = {rowR, esR, elr, err, fsR};
    a0.b = b0; a0.op = op0; a0.oa = oa0;
    AggArgs a1 = a0;
    a1.b = b1; a1.op = op1; a1.oa = oa1;

    // ---- launches ----
    k_scale<<<(N_A * IN_D / 4 + 255) / 256, 256, 0, stream>>>(x_author, x_paper, ntype, ha, hp);

    // CSR build (edge lists constant across layers)
    k_zero<<<(3 * 16384 + 255) / 256, 256, 0, stream>>>(cnt);
    k_hist<<<3 * NE / 256, 256, 0, stream>>>(dstW, dstC, dstR, cnt);
    k_scan<<<3, 1024, 0, stream>>>(cnt, row, cur);
    k_scatter<<<3 * NE / 256, 256, 0, stream>>>(srcW, dstW, srcC, dstC, srcR, dstR, cur, esW, esC, esR);

    // layer 0
    k_gemm<IN_D, 0><<<dim3(N_A / 128, 1, 5), 256, 0, stream>>>(j0);
    k_agg<<<(N_P + N_A) / 4, 256, 0, stream>>>(a0);

    // layer 1 (relu folded into GEMM X loads)
    k_gemm<HID, 1><<<dim3(N_A / 128, 1, 5), 256, 0, stream>>>(j1);
    k_agg<<<(N_P + N_A) / 4, 256, 0, stream>>>(a1);

    // epilogue
    k_hf<<<N_P / 4, 256, 0, stream>>>(op1, hf, ln1gb, attw, attb, ln2gb, fw1, fb1, fw2, fb2);
    k_gemm_out<<<dim3(N_P / 64, (OUTD + 63) / 64), 256, 0, stream>>>(hf, linW, linb, out);
}